// Round 5
// baseline (65.528 us; speedup 1.0000x reference)
//
#include <hip/hip_runtime.h>
#include <hip/hip_bf16.h>

// Conv2d: B=16, CIN=128, COUT=256, H=W=56, 3x3, stride1, pad1, fp32, + bias.
// Implicit GEMM, bf16 MFMA. M=256(co), N=16*56*64=57344(px, W padded 64), K=1152.
// R5: 256x256x64 tile, 8 waves, 2-buffer (128KB), 4-phase/tile 8-phase-template port:
// k-half-split LDS blocks (A[kh][256][32k], 64B rows -> conflict-free, NO swizzle),
// per-phase {ds_read quad || stage 1 half-tile || 16 MFMA}, raw barriers,
// counted vmcnt(4) at phases 1&3 only (T3+T4), setprio (T5), XCD swizzle (T1).

#define XT_BYTES   15204352u   // 16*58*64*128*2
#define SLACK      8192u
#define WT_OFFSET  (XT_BYTES + SLACK)
#define WT_BYTES   589824u     // 18 * 32768
#define WS_NEED    (WT_OFFSET + WT_BYTES)

typedef __bf16 bf16x8 __attribute__((ext_vector_type(8)));
typedef float  f32x4  __attribute__((ext_vector_type(4)));
typedef unsigned short ushort8v __attribute__((ext_vector_type(8)));

#define BAR()  __builtin_amdgcn_s_barrier()
#define SB0()  __builtin_amdgcn_sched_barrier(0)
#define LGKM0() asm volatile("s_waitcnt lgkmcnt(0)" ::: "memory")

__device__ __forceinline__ unsigned short f2bf(float f) {
  unsigned u = __builtin_bit_cast(unsigned, f);
  u += 0x7fffu + ((u >> 16) & 1u);
  return (unsigned short)(u >> 16);
}

__device__ __forceinline__ void gll16(const void* g, const void* l) {
  __builtin_amdgcn_global_load_lds(
      (const __attribute__((address_space(1))) unsigned int*)g,
      (__attribute__((address_space(3))) unsigned int*)l, 16, 0, 0);
}

// ---------------- fused prep kernel ----------------
// blocks 0..895: xtrans for (b,h) + zero pad-cols of that row
// blocks 896..927: zero rows 0 / 57 per image
// blocks 928..945: wtrans K-tile kt -> wt[kt][kh][co 0-255][32k] linear
__global__ void prep(const float* __restrict__ x, const float* __restrict__ wsrc,
                     unsigned short* __restrict__ xt, unsigned short* __restrict__ wt) {
  int blk = blockIdx.x;
  int t = threadIdx.x;   // 256
  if (blk < 896) {
    __shared__ unsigned short tile[128][58];
    int b = blk / 56, h = blk % 56;
    int ci = t >> 1, half = t & 1;
    const float* src = x + ((size_t)(b * 128 + ci)) * 3136 + h * 56 + half * 28;
    #pragma unroll
    for (int q = 0; q < 7; ++q) {
      float4 v = *(const float4*)&src[q * 4];
      int wb = half * 28 + q * 4;
      tile[ci][wb + 0] = f2bf(v.x);
      tile[ci][wb + 1] = f2bf(v.y);
      tile[ci][wb + 2] = f2bf(v.z);
      tile[ci][wb + 3] = f2bf(v.w);
    }
    unsigned short* row = xt + (size_t)b * 475136 + (size_t)(h + 1) * 8192;
    if (t < 128) {  // zero pad cols 0, 57..63 of this padded row
      int slot = t >> 4;
      int px = slot ? 56 + slot : 0;
      uint4 z; z.x = z.y = z.z = z.w = 0u;
      *(uint4*)(row + px * 128 + (t & 15) * 8) = z;
    }
    __syncthreads();
    if (t < 224) {
      int wo = t >> 2, chunk = t & 3;
      unsigned short* dst = row + (size_t)(wo + 1) * 128 + chunk * 32;
      #pragma unroll
      for (int q = 0; q < 4; ++q) {
        ushort8v v;
        #pragma unroll
        for (int j = 0; j < 8; ++j) v[j] = tile[chunk * 32 + q * 8 + j][wo];
        *(ushort8v*)&dst[q * 8] = v;
      }
    }
  } else if (blk < 928) {
    int idx = blk - 896;
    int b = idx >> 1, zr = (idx & 1) ? 57 : 0;
    uint4* dst = (uint4*)(xt + (size_t)b * 475136 + (size_t)zr * 8192);
    uint4 z; z.x = z.y = z.z = z.w = 0u;
    #pragma unroll
    for (int q = 0; q < 4; ++q) dst[t + q * 256] = z;
  } else {
    int kt = blk - 928;          // 0..17
    int tap = kt >> 1;
    int ci_base = (kt & 1) * 64;
    int co = t;
    #pragma unroll
    for (int khh = 0; khh < 2; ++khh) {
      const float* src = wsrc + (size_t)co * 1152 + (size_t)(ci_base + khh * 32) * 9 + tap;
      #pragma unroll
      for (int g = 0; g < 4; ++g) {
        ushort8v v;
        #pragma unroll
        for (int j = 0; j < 8; ++j) v[j] = f2bf(src[(g * 8 + j) * 9]);
        *(ushort8v*)&wt[(size_t)kt * 16384 + khh * 8192 + co * 32 + g * 8] = v;
      }
    }
  }
}

// ---------------- main GEMM kernel ----------------
// LDS buffer (64KB): A-kh0[256r][32k] @0, A-kh1 @16384, B-kh0 @32768, B-kh1 @49152.
// 64B rows; fragment read row*64 + lg*16 covers contiguous 1KB -> conflict-free.

__global__ __launch_bounds__(512, 2) void conv_gemm(
    const unsigned short* __restrict__ xt,
    const char* __restrict__ wtb,
    const float* __restrict__ bias,
    float* __restrict__ out) {
  __shared__ __align__(16) char lds[131072];   // 2 x 64KB

  int bid = blockIdx.x;
  int sw = (bid & 7) * 28 + (bid >> 3);        // XCD swizzle, 224 = 8*28
  int bimg = sw / 14;
  int h0 = (sw - bimg * 14) * 4;               // 4 output rows per tile

  int tid = threadIdx.x;
  int wv = tid >> 6, l = tid & 63;
  int wm = wv >> 2, wn = wv & 3;               // 2M x 4N waves, 128x64 each
  int lm = l & 15, lg = l >> 4;

  // fragment read byte offsets within a kh block
  int aRd = (wm * 128 + lm) * 64 + lg * 16;
  int bRd = 32768 + (wn * 64 + lm) * 64 + lg * 16;

  // staging sources
  const char* aS = wtb + tid * 16;             // A: fully linear
  int px0 = tid >> 2, q = tid & 3;
  const unsigned short* bS0 = xt +
      ((size_t)((bimg * 58 + h0 + (px0 >> 6)) * 64 + (px0 & 63))) * 128 + q * 8;
  int px1 = 128 + px0;
  const unsigned short* bS1 = xt +
      ((size_t)((bimg * 58 + h0 + (px1 >> 6)) * 64 + (px1 & 63))) * 128 + q * 8;

  f32x4 acc[8][4];
  #pragma unroll
  for (int m = 0; m < 8; ++m)
    #pragma unroll
    for (int n = 0; n < 4; ++n)
      acc[m][n] = (f32x4){0.f, 0.f, 0.f, 0.f};

  auto stageA = [&](int kt, int khh, char* nb) {
    const char* s = aS + kt * 32768 + khh * 16384;
    char* d = nb + khh * 16384 + tid * 16;
    gll16(s, d);
    gll16(s + 8192, d + 8192);
  };
  auto stageB = [&](int kt, int khh, char* nb) {
    int tap = kt >> 1;
    int kh_t = tap >= 6 ? 2 : (tap >= 3 ? 1 : 0);
    int kw_t = tap - 3 * kh_t;
    int koff = (kh_t * 64 + kw_t) * 128 + (kt & 1) * 64 + khh * 32;  // ushort units
    char* d = nb + 32768 + khh * 16384 + tid * 16;
    gll16(bS0 + koff, d);
    gll16(bS1 + koff, d + 8192);
  };

  // prologue: stage kt0's 4 half-tiles; retire kh0 pair only
  {
    char* b0 = &lds[0];
    stageA(0, 0, b0); stageB(0, 0, b0);
    stageA(0, 1, b0); stageB(0, 1, b0);
  }
  asm volatile("s_waitcnt vmcnt(4)" ::: "memory");
  SB0(); BAR(); SB0();

  for (int kt = 0; kt < 18; ++kt) {
    const char* base = &lds[(kt & 1) * 65536];
    char* nbase = &lds[((kt & 1) ^ 1) * 65536];
    bf16x8 a[4], bb[4];

    // ---- ph0: (mh0, kh0) ----
    #pragma unroll
    for (int m = 0; m < 4; ++m) a[m] = *(const bf16x8*)(base + aRd + m * 1024);
    #pragma unroll
    for (int n = 0; n < 4; ++n) bb[n] = *(const bf16x8*)(base + bRd + n * 1024);
    if (kt < 17) stageA(kt + 1, 0, nbase);
    SB0(); BAR(); LGKM0(); SB0();
    __builtin_amdgcn_s_setprio(1);
    #pragma unroll
    for (int m = 0; m < 4; ++m)
      #pragma unroll
      for (int n = 0; n < 4; ++n)
        acc[m][n] = __builtin_amdgcn_mfma_f32_16x16x32_bf16(a[m], bb[n], acc[m][n], 0, 0, 0);
    __builtin_amdgcn_s_setprio(0);
    SB0(); BAR(); SB0();

    // ---- ph1: (mh1, kh0) ----
    #pragma unroll
    for (int m = 0; m < 4; ++m) a[m] = *(const bf16x8*)(base + aRd + 4096 + m * 1024);
    if (kt < 17) stageB(kt + 1, 0, nbase);
    SB0(); BAR(); LGKM0(); SB0();
    __builtin_amdgcn_s_setprio(1);
    #pragma unroll
    for (int m = 0; m < 4; ++m)
      #pragma unroll
      for (int n = 0; n < 4; ++n)
        acc[m + 4][n] = __builtin_amdgcn_mfma_f32_16x16x32_bf16(a[m], bb[n], acc[m + 4][n], 0, 0, 0);
    __builtin_amdgcn_s_setprio(0);
    // retire this tile's kh1 half-tiles (read next phase); keep kt+1's kh0 in flight
    if (kt < 17) asm volatile("s_waitcnt vmcnt(4)" ::: "memory");
    else         asm volatile("s_waitcnt vmcnt(0)" ::: "memory");
    SB0(); BAR(); SB0();

    // ---- ph2: (mh0, kh1) ----
    #pragma unroll
    for (int m = 0; m < 4; ++m) a[m] = *(const bf16x8*)(base + 16384 + aRd + m * 1024);
    #pragma unroll
    for (int n = 0; n < 4; ++n) bb[n] = *(const bf16x8*)(base + 16384 + bRd + n * 1024);
    if (kt < 17) stageA(kt + 1, 1, nbase);
    SB0(); BAR(); LGKM0(); SB0();
    __builtin_amdgcn_s_setprio(1);
    #pragma unroll
    for (int m = 0; m < 4; ++m)
      #pragma unroll
      for (int n = 0; n < 4; ++n)
        acc[m][n] = __builtin_amdgcn_mfma_f32_16x16x32_bf16(a[m], bb[n], acc[m][n], 0, 0, 0);
    __builtin_amdgcn_s_setprio(0);
    SB0(); BAR(); SB0();

    // ---- ph3: (mh1, kh1) ----
    #pragma unroll
    for (int m = 0; m < 4; ++m) a[m] = *(const bf16x8*)(base + 16384 + aRd + 4096 + m * 1024);
    if (kt < 17) stageB(kt + 1, 1, nbase);
    SB0(); BAR(); LGKM0(); SB0();
    __builtin_amdgcn_s_setprio(1);
    #pragma unroll
    for (int m = 0; m < 4; ++m)
      #pragma unroll
      for (int n = 0; n < 4; ++n)
        acc[m + 4][n] = __builtin_amdgcn_mfma_f32_16x16x32_bf16(a[m], bb[n], acc[m + 4][n], 0, 0, 0);
    __builtin_amdgcn_s_setprio(0);
    // retire kt+1's kh0 half-tiles (read at kt+1 ph0); keep its kh1 in flight
    if (kt < 17) asm volatile("s_waitcnt vmcnt(4)" ::: "memory");
    SB0(); BAR(); SB0();
  }

  // epilogue: bias + masked store (w' < 56)
  #pragma unroll
  for (int m = 0; m < 8; ++m) {
    int co = wm * 128 + m * 16 + lg * 4;
    f32x4 bb = *(const f32x4*)&bias[co];
    size_t obase = ((size_t)bimg * 256 + co) * 3136;
    #pragma unroll
    for (int n = 0; n < 4; ++n) {
      int px = wn * 64 + n * 16 + lm;
      int w_ = px & 63;
      int h_ = h0 + (px >> 6);
      if (w_ < 56) {
        float* o = out + obase + (size_t)h_ * 56 + w_;
        #pragma unroll
        for (int r = 0; r < 4; ++r)
          o[(size_t)r * 3136] = acc[m][n][r] + bb[r];
      }
    }
  }
}

// ---------------- fallback (tiny ws) ----------------

__global__ void conv_naive(const float* __restrict__ x, const float* __restrict__ w,
                           const float* __restrict__ bias, float* __restrict__ out) {
  int idx = blockIdx.x * 256 + threadIdx.x;
  if (idx >= 16 * 256 * 56 * 56) return;
  int wo = idx % 56; int t = idx / 56;
  int ho = t % 56; t /= 56;
  int co = t % 256; int b = t / 256;
  float acc = bias[co];
  for (int ci = 0; ci < 128; ++ci) {
    const float* xp = x + ((size_t)(b * 128 + ci)) * 3136;
    const float* wp = w + ((size_t)(co * 128 + ci)) * 9;
    for (int kh = 0; kh < 3; ++kh) {
      int hi = ho + kh - 1;
      if (hi < 0 || hi >= 56) continue;
      for (int kw = 0; kw < 3; ++kw) {
        int wi = wo + kw - 1;
        if (wi < 0 || wi >= 56) continue;
        acc += xp[hi * 56 + wi] * wp[kh * 3 + kw];
      }
    }
  }
  out[idx] = acc;
}

extern "C" void kernel_launch(void* const* d_in, const int* in_sizes, int n_in,
                              void* d_out, int out_size, void* d_ws, size_t ws_size,
                              hipStream_t stream) {
  const float* x    = (const float*)d_in[0];
  const float* wgt  = (const float*)d_in[1];
  const float* bias = (const float*)d_in[2];
  float* out = (float*)d_out;

  if (ws_size < (size_t)WS_NEED) {
    conv_naive<<<(16 * 256 * 56 * 56 + 255) / 256, 256, 0, stream>>>(x, wgt, bias, out);
    return;
  }

  unsigned short* xt = (unsigned short*)d_ws;
  unsigned short* wt = (unsigned short*)((char*)d_ws + WT_OFFSET);

  prep<<<946, 256, 0, stream>>>(x, wgt, xt, wt);
  conv_gemm<<<224, 512, 0, stream>>>(xt, (const char*)wt, bias, out);
}

// Round 6
// 63.487 us; speedup vs baseline: 1.0321x; 1.0321x over previous
//
#include <hip/hip_runtime.h>
#include <hip/hip_bf16.h>

// Conv2d: B=16, CIN=128, COUT=256, H=W=56, 3x3, stride1, pad1, fp32, + bias.
// Implicit GEMM, bf16 MFMA. M=256(co), N=16*56*64=57344(px, W padded 64), K=1152.
// R6: 256x256x64 tile, 8 waves, 2-buffer (128KB), R3's PROVEN conflict-free
// XOR-swizzled LDS layout (measured 0 conflicts) + m201-style 4-phase/tile:
// ph0{12 ds_read|BAR|lgkm0|16 MFMA|BAR} ph1{8 ds_read|BAR|16 MFMA|lgkm0|BAR}
// ph2{4 ds_read + stageA(kt+2)|BAR|lgkm0|16 MFMA|BAR} ph3{stageB(kt+2)|BAR|16 MFMA|vmcnt(8)|BAR}
// Counted vmcnt never 0 until kt=16 (T4). setprio (T5), XCD swizzle (T1).

#define XT_BYTES   15204352u   // 16*58*64*128*2
#define SLACK      8192u
#define WT_OFFSET  (XT_BYTES + SLACK)
#define WT_BYTES   589824u     // 18 * 32768
#define WS_NEED    (WT_OFFSET + WT_BYTES)

typedef __bf16 bf16x8 __attribute__((ext_vector_type(8)));
typedef float  f32x4  __attribute__((ext_vector_type(4)));
typedef unsigned short ushort8v __attribute__((ext_vector_type(8)));

#define BAR()   __builtin_amdgcn_s_barrier()
#define SB0()   __builtin_amdgcn_sched_barrier(0)
#define LGKM0() asm volatile("s_waitcnt lgkmcnt(0)" ::: "memory")

__device__ __forceinline__ unsigned short f2bf(float f) {
  unsigned u = __builtin_bit_cast(unsigned, f);
  u += 0x7fffu + ((u >> 16) & 1u);
  return (unsigned short)(u >> 16);
}

__device__ __forceinline__ void gll16(const void* g, const void* l) {
  __builtin_amdgcn_global_load_lds(
      (const __attribute__((address_space(1))) unsigned int*)g,
      (__attribute__((address_space(3))) unsigned int*)l, 16, 0, 0);
}

// ---------------- fused prep kernel (identical to R3, verified) ----------------
__global__ void prep(const float* __restrict__ x, const float* __restrict__ wsrc,
                     unsigned short* __restrict__ xt, unsigned short* __restrict__ wt) {
  int blk = blockIdx.x;
  int t = threadIdx.x;   // 256
  if (blk < 896) {
    __shared__ unsigned short tile[128][58];
    int b = blk / 56, h = blk % 56;
    int ci = t >> 1, half = t & 1;
    const float* src = x + ((size_t)(b * 128 + ci)) * 3136 + h * 56 + half * 28;
    #pragma unroll
    for (int q = 0; q < 7; ++q) {
      float4 v = *(const float4*)&src[q * 4];
      int wb = half * 28 + q * 4;
      tile[ci][wb + 0] = f2bf(v.x);
      tile[ci][wb + 1] = f2bf(v.y);
      tile[ci][wb + 2] = f2bf(v.z);
      tile[ci][wb + 3] = f2bf(v.w);
    }
    unsigned short* row = xt + (size_t)b * 475136 + (size_t)(h + 1) * 8192;
    if (t < 128) {  // zero pad cols 0, 57..63 of this padded row
      int slot = t >> 4;
      int px = slot ? 56 + slot : 0;
      uint4 z; z.x = z.y = z.z = z.w = 0u;
      *(uint4*)(row + px * 128 + (t & 15) * 8) = z;
    }
    __syncthreads();
    if (t < 224) {
      int wo = t >> 2, chunk = t & 3;
      unsigned short* dst = row + (size_t)(wo + 1) * 128 + chunk * 32;
      #pragma unroll
      for (int q = 0; q < 4; ++q) {
        ushort8v v;
        #pragma unroll
        for (int j = 0; j < 8; ++j) v[j] = tile[chunk * 32 + q * 8 + j][wo];
        *(ushort8v*)&dst[q * 8] = v;
      }
    }
  } else if (blk < 928) {
    int idx = blk - 896;
    int b = idx >> 1, zr = (idx & 1) ? 57 : 0;
    uint4* dst = (uint4*)(xt + (size_t)b * 475136 + (size_t)zr * 8192);
    uint4 z; z.x = z.y = z.z = z.w = 0u;
    #pragma unroll
    for (int q = 0; q < 4; ++q) dst[t + q * 256] = z;
  } else {
    int kt = blk - 928;          // 0..17
    int tap = kt >> 1;
    int ci0 = (kt & 1) * 64;
    #pragma unroll
    for (int q = 0; q < 8; ++q) {
      int n = t + q * 256;       // 0..2047
      int co = n >> 3;
      int kg = (n & 7) ^ (co & 7);
      const float* src = wsrc + (size_t)co * 1152 + (size_t)(ci0 + kg * 8) * 9 + tap;
      ushort8v v;
      #pragma unroll
      for (int j = 0; j < 8; ++j) v[j] = f2bf(src[j * 9]);
      *(ushort8v*)&wt[(size_t)kt * 16384 + n * 8] = v;
    }
  }
}

// ---------------- main GEMM kernel ----------------
// LDS buffer (64KB): A [256co][64k] at +0, B [256px][64k] at +32768.
// swizzle: byte(r,k) = r*128 + ((k>>3) ^ (r&7))*16 + (k&7)*2   (measured 0-conflict)

__global__ __launch_bounds__(512, 2) void conv_gemm(
    const unsigned short* __restrict__ xt,
    const char* __restrict__ wt,
    const float* __restrict__ bias,
    float* __restrict__ out) {
  __shared__ __align__(16) char lds[131072];   // 2 x 64KB

  int bid = blockIdx.x;
  int sw = (bid & 7) * 28 + (bid >> 3);        // XCD swizzle, 224 = 8*28
  int bimg = sw / 14;
  int h0 = (sw - bimg * 14) * 4;               // 4 output rows per tile

  int tid = threadIdx.x;
  int wv = tid >> 6, l = tid & 63;
  int wm = wv >> 2, wn = wv & 3;               // 2M x 4N waves, 128x64 each
  int lm = l & 15, lg = l >> 4, x7 = lm & 7;

  int aoff0 = wm * 16384 + lm * 128 + ((lg ^ x7) << 4);
  int boff0 = 32768 + wn * 8192 + lm * 128 + ((lg ^ x7) << 4);

  // staging sources (LDS dest linear; inverse swizzle folded into source)
  const char* aB = wt + wv * 4096 + l * 16;
  const unsigned short* bB[4];
  #pragma unroll
  for (int q = 0; q < 4; ++q) {
    int n = wv * 256 + q * 64 + l;
    int px = n >> 3;
    int kg = (n & 7) ^ (px & 7);
    bB[q] = xt + ((size_t)((bimg * 58 + h0 + (px >> 6)) * 64 + (px & 63))) * 128 + kg * 8;
  }

  f32x4 acc[8][4];
  #pragma unroll
  for (int m = 0; m < 8; ++m)
    #pragma unroll
    for (int n = 0; n < 4; ++n)
      acc[m][n] = (f32x4){0.f, 0.f, 0.f, 0.f};

  auto stageA = [&](int kt, int buf) {
    const char* sA = aB + kt * 32768;
    char* dA = &lds[buf * 65536 + wv * 4096];
    #pragma unroll
    for (int q = 0; q < 4; ++q) gll16(sA + q * 1024, dA + q * 1024);
  };
  auto stageB = [&](int kt, int buf) {
    int tap = kt >> 1;
    int kh = tap >= 6 ? 2 : (tap >= 3 ? 1 : 0);
    int kw = tap - kh * 3;
    int koff = (kh * 64 + kw) * 128 + (kt & 1) * 64;   // ushort units
    char* dB = &lds[buf * 65536 + 32768 + wv * 4096];
    #pragma unroll
    for (int q = 0; q < 4; ++q) gll16(bB[q] + koff, dB + q * 1024);
  };

  // prologue: both buffers staged; retire tile0's 8, keep tile1's 8 in flight
  stageA(0, 0); stageB(0, 0);
  stageA(1, 1); stageB(1, 1);
  asm volatile("s_waitcnt vmcnt(8)" ::: "memory");
  SB0(); BAR(); SB0();

  for (int kt = 0; kt < 18; ++kt) {
    const char* base = &lds[(kt & 1) * 65536];
    int cur = kt & 1;
    bf16x8 a0[8], a1[8], bb0[4], bb1[4];

    // ---- ph0: read all a_kh0 + b_kh0; MFMA (mh0, kh0) ----
    #pragma unroll
    for (int m = 0; m < 8; ++m) a0[m] = *(const bf16x8*)(base + aoff0 + m * 2048);
    #pragma unroll
    for (int n = 0; n < 4; ++n) bb0[n] = *(const bf16x8*)(base + boff0 + n * 2048);
    SB0(); BAR(); LGKM0(); SB0();
    __builtin_amdgcn_s_setprio(1);
    #pragma unroll
    for (int m = 0; m < 4; ++m)
      #pragma unroll
      for (int n = 0; n < 4; ++n)
        acc[m][n] = __builtin_amdgcn_mfma_f32_16x16x32_bf16(a0[m], bb0[n], acc[m][n], 0, 0, 0);
    __builtin_amdgcn_s_setprio(0);
    SB0(); BAR(); SB0();

    // ---- ph1: read all a_kh1 (overlaps MFMA); MFMA (mh1, kh0) ----
    #pragma unroll
    for (int m = 0; m < 8; ++m) a1[m] = *(const bf16x8*)(base + ((aoff0 ^ 64) + m * 2048));
    SB0(); BAR(); SB0();
    __builtin_amdgcn_s_setprio(1);
    #pragma unroll
    for (int m = 0; m < 4; ++m)
      #pragma unroll
      for (int n = 0; n < 4; ++n)
        acc[m + 4][n] = __builtin_amdgcn_mfma_f32_16x16x32_bf16(a0[m + 4], bb0[n], acc[m + 4][n], 0, 0, 0);
    __builtin_amdgcn_s_setprio(0);
    LGKM0();           // all A reads complete -> A region WAR-safe after barrier
    SB0(); BAR(); SB0();

    // ---- ph2: read b_kh1; stage kt+2's A into cur; MFMA (mh0, kh1) ----
    #pragma unroll
    for (int n = 0; n < 4; ++n) bb1[n] = *(const bf16x8*)(base + ((boff0 ^ 64) + n * 2048));
    if (kt < 16) stageA(kt + 2, cur);
    SB0(); BAR(); LGKM0(); SB0();
    __builtin_amdgcn_s_setprio(1);
    #pragma unroll
    for (int m = 0; m < 4; ++m)
      #pragma unroll
      for (int n = 0; n < 4; ++n)
        acc[m][n] = __builtin_amdgcn_mfma_f32_16x16x32_bf16(a1[m], bb1[n], acc[m][n], 0, 0, 0);
    __builtin_amdgcn_s_setprio(0);
    SB0(); BAR(); SB0();

    // ---- ph3: stage kt+2's B into cur; MFMA (mh1, kh1); counted vmcnt ----
    if (kt < 16) stageB(kt + 2, cur);
    SB0(); BAR(); SB0();
    __builtin_amdgcn_s_setprio(1);
    #pragma unroll
    for (int m = 0; m < 4; ++m)
      #pragma unroll
      for (int n = 0; n < 4; ++n)
        acc[m + 4][n] = __builtin_amdgcn_mfma_f32_16x16x32_bf16(a1[m + 4], bb1[n], acc[m + 4][n], 0, 0, 0);
    __builtin_amdgcn_s_setprio(0);
    if (kt < 16)       asm volatile("s_waitcnt vmcnt(8)" ::: "memory");
    else if (kt == 16) asm volatile("s_waitcnt vmcnt(0)" ::: "memory");
    SB0(); BAR(); SB0();
  }

  // epilogue: bias + masked store (w' < 56)
  #pragma unroll
  for (int m = 0; m < 8; ++m) {
    int co = wm * 128 + m * 16 + lg * 4;
    f32x4 bb = *(const f32x4*)&bias[co];
    size_t obase = ((size_t)bimg * 256 + co) * 3136;
    #pragma unroll
    for (int n = 0; n < 4; ++n) {
      int px = wn * 64 + n * 16 + lm;
      int w_ = px & 63;
      int h_ = h0 + (px >> 6);
      if (w_ < 56) {
        float* o = out + obase + (size_t)h_ * 56 + w_;
        #pragma unroll
        for (int r = 0; r < 4; ++r)
          o[(size_t)r * 3136] = acc[m][n][r] + bb[r];
      }
    }
  }
}

// ---------------- fallback (tiny ws) ----------------

__global__ void conv_naive(const float* __restrict__ x, const float* __restrict__ w,
                           const float* __restrict__ bias, float* __restrict__ out) {
  int idx = blockIdx.x * 256 + threadIdx.x;
  if (idx >= 16 * 256 * 56 * 56) return;
  int wo = idx % 56; int t = idx / 56;
  int ho = t % 56; t /= 56;
  int co = t % 256; int b = t / 256;
  float acc = bias[co];
  for (int ci = 0; ci < 128; ++ci) {
    const float* xp = x + ((size_t)(b * 128 + ci)) * 3136;
    const float* wp = w + ((size_t)(co * 128 + ci)) * 9;
    for (int kh = 0; kh < 3; ++kh) {
      int hi = ho + kh - 1;
      if (hi < 0 || hi >= 56) continue;
      for (int kw = 0; kw < 3; ++kw) {
        int wi = wo + kw - 1;
        if (wi < 0 || wi >= 56) continue;
        acc += xp[hi * 56 + wi] * wp[kh * 3 + kw];
      }
    }
  }
  out[idx] = acc;
}

extern "C" void kernel_launch(void* const* d_in, const int* in_sizes, int n_in,
                              void* d_out, int out_size, void* d_ws, size_t ws_size,
                              hipStream_t stream) {
  const float* x    = (const float*)d_in[0];
  const float* wgt  = (const float*)d_in[1];
  const float* bias = (const float*)d_in[2];
  float* out = (float*)d_out;

  if (ws_size < (size_t)WS_NEED) {
    conv_naive<<<(16 * 256 * 56 * 56 + 255) / 256, 256, 0, stream>>>(x, wgt, bias, out);
    return;
  }

  unsigned short* xt = (unsigned short*)d_ws;
  unsigned short* wt = (unsigned short*)((char*)d_ws + WT_OFFSET);

  prep<<<946, 256, 0, stream>>>(x, wgt, xt, wt);
  conv_gemm<<<224, 512, 0, stream>>>(xt, (const char*)wt, bias, out);
}

// Round 7
// 58.402 us; speedup vs baseline: 1.1220x; 1.0871x over previous
//
#include <hip/hip_runtime.h>
#include <hip/hip_bf16.h>

// Conv2d: B=16, CIN=128, COUT=256, H=W=56, 3x3, stride1, pad1, fp32, + bias.
// Implicit GEMM, bf16 MFMA. M=256(co), N=16*56*64=57344(px, W padded 64), K=1152.
// R7: 128x128 tile, BK=64, 4 waves, 2-buffer 64KB LDS -> 2 blocks/CU (m97/m114
// implicit inter-block overlap). R3's best-measured loop: issue-stage-early,
// ONE __syncthreads per K-tile, setprio clusters, proven 0-conflict XOR swizzle,
// pre-swizzled linear A staging + pre-swizzled per-lane B sources. Grid 896=8*112 (T1).

#define XT_BYTES   15204352u   // 16*58*64*128*2
#define SLACK      8192u
#define WT_OFFSET  (XT_BYTES + SLACK)
#define WT_BYTES   589824u     // 18 kt * 2 pm * 16KB
#define WS_NEED    (WT_OFFSET + WT_BYTES)

typedef __bf16 bf16x8 __attribute__((ext_vector_type(8)));
typedef float  f32x4  __attribute__((ext_vector_type(4)));
typedef unsigned short ushort8v __attribute__((ext_vector_type(8)));

__device__ __forceinline__ unsigned short f2bf(float f) {
  unsigned u = __builtin_bit_cast(unsigned, f);
  u += 0x7fffu + ((u >> 16) & 1u);
  return (unsigned short)(u >> 16);
}

__device__ __forceinline__ void gll16(const void* g, const void* l) {
  __builtin_amdgcn_global_load_lds(
      (const __attribute__((address_space(1))) unsigned int*)g,
      (__attribute__((address_space(3))) unsigned int*)l, 16, 0, 0);
}

// ---------------- fused prep kernel ----------------
// blocks 0..895: xtrans for (b,h) + zero pad-cols of that row
// blocks 896..927: zero rows 0 / 57 per image
// blocks 928..945: wtrans K-tile kt -> wt[kt][pm][1024 slots x 16B] pre-swizzled
__global__ void prep(const float* __restrict__ x, const float* __restrict__ wsrc,
                     unsigned short* __restrict__ xt, unsigned short* __restrict__ wt) {
  int blk = blockIdx.x;
  int t = threadIdx.x;   // 256
  if (blk < 896) {
    __shared__ unsigned short tile[128][58];
    int b = blk / 56, h = blk % 56;
    int ci = t >> 1, half = t & 1;
    const float* src = x + ((size_t)(b * 128 + ci)) * 3136 + h * 56 + half * 28;
    #pragma unroll
    for (int q = 0; q < 7; ++q) {
      float4 v = *(const float4*)&src[q * 4];
      int wb = half * 28 + q * 4;
      tile[ci][wb + 0] = f2bf(v.x);
      tile[ci][wb + 1] = f2bf(v.y);
      tile[ci][wb + 2] = f2bf(v.z);
      tile[ci][wb + 3] = f2bf(v.w);
    }
    unsigned short* row = xt + (size_t)b * 475136 + (size_t)(h + 1) * 8192;
    if (t < 128) {  // zero pad cols 0, 57..63 of this padded row
      int slot = t >> 4;
      int px = slot ? 56 + slot : 0;
      uint4 z; z.x = z.y = z.z = z.w = 0u;
      *(uint4*)(row + px * 128 + (t & 15) * 8) = z;
    }
    __syncthreads();
    if (t < 224) {
      int wo = t >> 2, chunk = t & 3;
      unsigned short* dst = row + (size_t)(wo + 1) * 128 + chunk * 32;
      #pragma unroll
      for (int q = 0; q < 4; ++q) {
        ushort8v v;
        #pragma unroll
        for (int j = 0; j < 8; ++j) v[j] = tile[chunk * 32 + q * 8 + j][wo];
        *(ushort8v*)&dst[q * 8] = v;
      }
    }
  } else if (blk < 928) {
    int idx = blk - 896;
    int b = idx >> 1, zr = (idx & 1) ? 57 : 0;
    uint4* dst = (uint4*)(xt + (size_t)b * 475136 + (size_t)zr * 8192);
    uint4 z; z.x = z.y = z.z = z.w = 0u;
    #pragma unroll
    for (int q = 0; q < 4; ++q) dst[t + q * 256] = z;
  } else {
    int kt = blk - 928;          // 0..17
    int tap = kt >> 1;
    int ci0 = (kt & 1) * 64;
    #pragma unroll
    for (int q = 0; q < 8; ++q) {
      int n2 = t + q * 256;      // 0..2047
      int pm = n2 >> 10, n = n2 & 1023;
      int r = n >> 3;
      int co = pm * 128 + r;
      int kg = (n & 7) ^ (r & 7);
      const float* src = wsrc + (size_t)co * 1152 + (size_t)(ci0 + kg * 8) * 9 + tap;
      ushort8v v;
      #pragma unroll
      for (int j = 0; j < 8; ++j) v[j] = f2bf(src[j * 9]);
      *(ushort8v*)&wt[(size_t)kt * 16384 + pm * 8192 + n * 8] = v;
    }
  }
}

// ---------------- main GEMM kernel ----------------
// LDS buffer (32KB): A [128co][64k] at +0, B [128px][64k] at +16384.
// swizzle: byte(r,k) = r*128 + ((k>>3) ^ (r&7))*16 + (k&7)*2   (measured 0-conflict)

__global__ __launch_bounds__(256, 2) void conv_gemm(
    const unsigned short* __restrict__ xt,
    const char* __restrict__ wt,
    const float* __restrict__ bias,
    float* __restrict__ out) {
  __shared__ __align__(16) char lds[65536];    // 2 x 32KB

  int bid = blockIdx.x;
  int sw = (bid & 7) * 112 + (bid >> 3);       // XCD swizzle, 896 = 8*112
  int pm = sw & 1;                             // co half
  int pn = sw >> 1;                            // 0..447 pixel tile
  int bimg = pn / 28;
  int h0 = (pn - bimg * 28) * 2;               // 2 output rows per tile

  int tid = threadIdx.x;
  int wv = tid >> 6, l = tid & 63;
  int wm = wv >> 1, wn = wv & 1;               // 2M x 2N waves, 64x64 each
  int lm = l & 15, lg = l >> 4, x7 = lm & 7;

  int aoff0 = wm * 8192 + lm * 128 + ((lg ^ x7) << 4);
  int boff0 = 16384 + wn * 8192 + lm * 128 + ((lg ^ x7) << 4);

  // staging sources (LDS dest linear; inverse swizzle folded into source)
  const char* aB = wt + pm * 16384 + wv * 4096 + l * 16;
  const unsigned short* bB[4];
  #pragma unroll
  for (int q = 0; q < 4; ++q) {
    int n = wv * 256 + q * 64 + l;             // 0..1023
    int px = n >> 3;                           // 0..127
    int kg = (n & 7) ^ (px & 7);
    bB[q] = xt + ((size_t)((bimg * 58 + h0 + (px >> 6)) * 64 + (px & 63))) * 128 + kg * 8;
  }

  f32x4 acc[4][4];
  #pragma unroll
  for (int m = 0; m < 4; ++m)
    #pragma unroll
    for (int n = 0; n < 4; ++n)
      acc[m][n] = (f32x4){0.f, 0.f, 0.f, 0.f};

  auto stage = [&](int kt, int buf) {
    int tap = kt >> 1;
    int kh = tap >= 6 ? 2 : (tap >= 3 ? 1 : 0);
    int kw = tap - kh * 3;
    int koff = (kh * 64 + kw) * 128 + (kt & 1) * 64;   // ushort units
    const char* sA = aB + kt * 32768;
    char* dA = &lds[buf * 32768 + wv * 4096];
    char* dB = &lds[buf * 32768 + 16384 + wv * 4096];
    #pragma unroll
    for (int q = 0; q < 4; ++q) {
      gll16(sA + q * 1024, dA + q * 1024);
      gll16(bB[q] + koff, dB + q * 1024);
    }
  };

  stage(0, 0);
  __syncthreads();

  for (int kt = 0; kt < 18; ++kt) {
    const char* base = &lds[(kt & 1) * 32768];
    if (kt < 17) stage(kt + 1, (kt + 1) & 1);   // issue-early: latency under compute
    bf16x8 a0[4], b0[4];
    #pragma unroll
    for (int m = 0; m < 4; ++m) a0[m] = *(const bf16x8*)(base + aoff0 + m * 2048);
    #pragma unroll
    for (int n = 0; n < 4; ++n) b0[n] = *(const bf16x8*)(base + boff0 + n * 2048);
    __builtin_amdgcn_s_setprio(1);
    #pragma unroll
    for (int m = 0; m < 4; ++m)
      #pragma unroll
      for (int n = 0; n < 4; ++n)
        acc[m][n] = __builtin_amdgcn_mfma_f32_16x16x32_bf16(a0[m], b0[n], acc[m][n], 0, 0, 0);
    __builtin_amdgcn_s_setprio(0);
    bf16x8 a1[4], b1[4];
    #pragma unroll
    for (int m = 0; m < 4; ++m) a1[m] = *(const bf16x8*)(base + ((aoff0 ^ 64) + m * 2048));
    #pragma unroll
    for (int n = 0; n < 4; ++n) b1[n] = *(const bf16x8*)(base + ((boff0 ^ 64) + n * 2048));
    __builtin_amdgcn_s_setprio(1);
    #pragma unroll
    for (int m = 0; m < 4; ++m)
      #pragma unroll
      for (int n = 0; n < 4; ++n)
        acc[m][n] = __builtin_amdgcn_mfma_f32_16x16x32_bf16(a1[m], b1[n], acc[m][n], 0, 0, 0);
    __builtin_amdgcn_s_setprio(0);
    if (kt < 17) __syncthreads();   // single sync point per K-tile
  }

  // epilogue: bias + masked store (w' < 56)
  #pragma unroll
  for (int m = 0; m < 4; ++m) {
    int co = pm * 128 + wm * 64 + m * 16 + lg * 4;
    f32x4 bb = *(const f32x4*)&bias[co];
    size_t obase = ((size_t)bimg * 256 + co) * 3136;
    #pragma unroll
    for (int n = 0; n < 4; ++n) {
      int px = wn * 64 + n * 16 + lm;
      int w_ = px & 63;
      int h_ = h0 + (px >> 6);
      if (w_ < 56) {
        float* o = out + obase + (size_t)h_ * 56 + w_;
        #pragma unroll
        for (int r = 0; r < 4; ++r)
          o[(size_t)r * 3136] = acc[m][n][r] + bb[r];
      }
    }
  }
}

// ---------------- fallback (tiny ws) ----------------

__global__ void conv_naive(const float* __restrict__ x, const float* __restrict__ w,
                           const float* __restrict__ bias, float* __restrict__ out) {
  int idx = blockIdx.x * 256 + threadIdx.x;
  if (idx >= 16 * 256 * 56 * 56) return;
  int wo = idx % 56; int t = idx / 56;
  int ho = t % 56; t /= 56;
  int co = t % 256; int b = t / 256;
  float acc = bias[co];
  for (int ci = 0; ci < 128; ++ci) {
    const float* xp = x + ((size_t)(b * 128 + ci)) * 3136;
    const float* wp = w + ((size_t)(co * 128 + ci)) * 9;
    for (int kh = 0; kh < 3; ++kh) {
      int hi = ho + kh - 1;
      if (hi < 0 || hi >= 56) continue;
      for (int kw = 0; kw < 3; ++kw) {
        int wi = wo + kw - 1;
        if (wi < 0 || wi >= 56) continue;
        acc += xp[hi * 56 + wi] * wp[kh * 3 + kw];
      }
    }
  }
  out[idx] = acc;
}

extern "C" void kernel_launch(void* const* d_in, const int* in_sizes, int n_in,
                              void* d_out, int out_size, void* d_ws, size_t ws_size,
                              hipStream_t stream) {
  const float* x    = (const float*)d_in[0];
  const float* wgt  = (const float*)d_in[1];
  const float* bias = (const float*)d_in[2];
  float* out = (float*)d_out;

  if (ws_size < (size_t)WS_NEED) {
    conv_naive<<<(16 * 256 * 56 * 56 + 255) / 256, 256, 0, stream>>>(x, wgt, bias, out);
    return;
  }

  unsigned short* xt = (unsigned short*)d_ws;
  unsigned short* wt = (unsigned short*)((char*)d_ws + WT_OFFSET);

  prep<<<946, 256, 0, stream>>>(x, wgt, xt, wt);
  conv_gemm<<<896, 256, 0, stream>>>(xt, (const char*)wt, bias, out);
}